// Round 1
// 563.079 us; speedup vs baseline: 1.0108x; 1.0108x over previous
//
#include <hip/hip_runtime.h>
#include <stdint.h>

#define DDIM 512
#define BROWS 65536
#define EPSF 1e-15f
#define MAXNF 0.996f
#define SQRT_EPSF 3.1622776e-8f
#define ATANH_CLIP 0.99999988f

typedef __bf16 bf16x8 __attribute__((ext_vector_type(8)));
typedef float f32x4 __attribute__((ext_vector_type(4)));

__device__ __forceinline__ unsigned short f2bf(float f) {
    union { float f; uint32_t u; } c; c.f = f;
    uint32_t u = c.u;
    u += 0x7fffu + ((u >> 16) & 1u);
    return (unsigned short)(u >> 16);
}

__device__ __forceinline__ float rcpf(float x) { return __builtin_amdgcn_rcpf(x); }

__device__ __forceinline__ float wred(float v) {
    v += __shfl_xor(v, 1);
    v += __shfl_xor(v, 2);
    v += __shfl_xor(v, 4);
    v += __shfl_xor(v, 8);
    v += __shfl_xor(v, 16);
    v += __shfl_xor(v, 32);
    return v;
}

// x >= 0
__device__ __forceinline__ float fast_tanh_pos(float x) {
    float t = __expf(-2.0f * x);
    return (1.0f - t) * rcpf(1.0f + t);
}
// 0 <= x < 1
__device__ __forceinline__ float fast_atanh_pos(float x) {
    return 0.5f * __logf((1.0f + x) * rcpf(1.0f - x));
}
__device__ __forceinline__ float fast_asinh(float t) {
    float a = fabsf(t);
    float r = __logf(a + sqrtf(fmaf(a, a, 1.0f)));
    return copysignf(r, t);
}
__device__ __forceinline__ float fast_sinh(float v) {
    float q = __expf(v);
    return 0.5f * (q - rcpf(q));
}

// ---------------- prep: zn, cosh/sinh(2b), transposed bf16 z_unit ----------------
__global__ void prep_kernel(const float* __restrict__ z, const float* __restrict__ bias,
                            float* __restrict__ znf, float* __restrict__ chv,
                            float* __restrict__ shv, unsigned short* __restrict__ zT) {
    int j = blockIdx.x;   // out column
    int l = threadIdx.x;  // 0..63
    float zv[8];
    float s = 0.f;
#pragma unroll
    for (int t = 0; t < 8; ++t) {
        float v = z[(size_t)(t * 64 + l) * DDIM + j];
        zv[t] = v;
        s = fmaf(v, v, s);
    }
    s = wred(s);
    float zn = sqrtf(fmaxf(s, EPSF));
    float inv = 1.0f / zn;
#pragma unroll
    for (int t = 0; t < 8; ++t)
        zT[(size_t)j * DDIM + t * 64 + l] = f2bf(zv[t] * inv);
    if (l == 0) {
        znf[j] = zn;
        float tr = 2.0f * bias[j];
        chv[j] = coshf(tr);
        shv[j] = sinhf(tr);
    }
}

// ---------------- fused main kernel ----------------
// 64 rows/block, 512 threads (8 waves), 2 blocks/CU.
__global__ __launch_bounds__(512, 4) void hpd_main(
    const float* __restrict__ Xc, const float* __restrict__ Xp,
    const float* __restrict__ znf, const float* __restrict__ chv, const float* __restrict__ shv,
    const unsigned short* __restrict__ zT,
    const float* __restrict__ alpha_p, const float* __restrict__ step_p,
    float* __restrict__ out)
{
    __shared__ __align__(16) unsigned char smem[70656];
    // [0,65536): e bf16 [64][512] XOR-swizzled (MFMA A staging)
    float* cx2s = (float*)(smem + 65536);   // 64
    float* dccs = (float*)(smem + 65792);   // 64
    float* swp  = (float*)(smem + 66048);   // [64][8]
    float* cwp  = (float*)(smem + 68096);   // [64][8]
    float* ans  = (float*)(smem + 70144);   // 64
    float* bns  = (float*)(smem + 70400);   // 64

    const int t = threadIdx.x;
    const int w = t >> 6;
    const int l = t & 63;
    const int l15 = l & 15;
    const int quad = l >> 4;
    const int r0 = blockIdx.x * 64;

    float a_sig = rcpf(1.0f + __expf(-alpha_p[0]));
    float step_sig = rcpf(1.0f + __expf(-step_p[0]));

    float* out1 = out + (size_t)BROWS * DDIM;

    // ---------------- Phase A: dots, bt, e, and xc output ----------------
    // Two groups of 4 rows: batch all 16 global loads per group (1 latency
    // exposure instead of 4), then 12 interleaved shuffle-reduce chains.
#pragma unroll
    for (int g = 0; g < 2; ++g) {
        const int rowb = w * 4 + (g << 5);
        float xcv[4][8], xpv[4][8];
#pragma unroll
        for (int q = 0; q < 4; ++q) {
            const float* pc = Xc + (size_t)(r0 + rowb + q) * DDIM + l * 8;
            const float* pp = Xp + (size_t)(r0 + rowb + q) * DDIM + l * 8;
            *(float4*)&xcv[q][0] = *(const float4*)pc;
            *(float4*)&xcv[q][4] = *(const float4*)(pc + 4);
            *(float4*)&xpv[q][0] = *(const float4*)pp;
            *(float4*)&xpv[q][4] = *(const float4*)(pp + 4);
        }
        float dcc[4], dpp[4], dpc[4];
#pragma unroll
        for (int q = 0; q < 4; ++q) {
            float a = 0.f, b = 0.f, c = 0.f;
#pragma unroll
            for (int j = 0; j < 8; ++j) {
                a = fmaf(xcv[q][j], xcv[q][j], a);
                b = fmaf(xpv[q][j], xpv[q][j], b);
                c = fmaf(xpv[q][j], xcv[q][j], c);
            }
            dcc[q] = a; dpp[q] = b; dpc[q] = c;
        }
        // 12 independent butterfly chains, level-interleaved (same order per
        // value as wred -> bit-identical results)
#pragma unroll
        for (int s = 1; s < 64; s <<= 1) {
#pragma unroll
            for (int q = 0; q < 4; ++q) {
                dcc[q] += __shfl_xor(dcc[q], s);
                dpp[q] += __shfl_xor(dpp[q], s);
                dpc[q] += __shfl_xor(dpc[q], s);
            }
        }
#pragma unroll
        for (int q = 0; q < 4; ++q) {
            const int row = rowb + q;
            // sub = mobius_add(-p, x) = (Ca*p + Cb*x)/den
            float Ca = -(1.0f - 2.0f * dpc[q] + dcc[q]);
            float Cb = 1.0f - dpp[q];
            float den = fmaxf(1.0f - 2.0f * dpc[q] + dpp[q] * dcc[q], EPSF);
            float rden = rcpf(den);
            float ssub = (Ca * Ca * dpp[q] + 2.0f * Ca * Cb * dpc[q] + Cb * Cb * dcc[q]) * rden * rden;
            float sn = sqrtf(fmaxf(ssub, EPSF));
            float tol = fmaxf(1.0f - dpp[q], EPSF);          // 2/lam
            float art = fast_atanh_pos(fminf(sn, ATANH_CLIP));
            float sbt = tol * art * rcpf(sn);                 // bt = sbt*sub
            float un = fmaxf(tol * art, SQRT_EPSF);           // ||bt||
            float te = fast_tanh_pos(un);
            float se = te * rcpf(un) * sbt;                   // e = se*sub
            float cep = se * Ca * rden;
            float cex = se * Cb * rden;
            if (l == 0) { cx2s[row] = te * te; dccs[row] = dcc[q]; }
            // xc = projx(x_current)  -> output 1, done right here
            float nx = sqrtf(fmaxf(dcc[q], EPSF));
            float sxc = (nx > MAXNF) ? (MAXNF * rcpf(nx)) : 1.0f;
            float* po1 = out1 + (size_t)(r0 + row) * DDIM + l * 8;
            *(float4*)po1 = make_float4(sxc * xcv[q][0], sxc * xcv[q][1], sxc * xcv[q][2], sxc * xcv[q][3]);
            *(float4*)(po1 + 4) = make_float4(sxc * xcv[q][4], sxc * xcv[q][5], sxc * xcv[q][6], sxc * xcv[q][7]);
            unsigned short e8[8];
#pragma unroll
            for (int j = 0; j < 8; ++j)
                e8[j] = f2bf(fmaf(cex, xcv[q][j], cep * xpv[q][j]));
            uint32_t u0 = (uint32_t)e8[0] | ((uint32_t)e8[1] << 16);
            uint32_t u1 = (uint32_t)e8[2] | ((uint32_t)e8[3] << 16);
            uint32_t u2 = (uint32_t)e8[4] | ((uint32_t)e8[5] << 16);
            uint32_t u3 = (uint32_t)e8[6] | ((uint32_t)e8[7] << 16);
            uint32_t off = row * 1024 + ((l ^ (row & 7)) * 16);
            *(uint4*)(smem + off) = make_uint4(u0, u1, u2, u3);
        }
    }
    __syncthreads();

    // ---------------- K-loop: inner = e @ z_unit ----------------
    // Fully unrolled with register double-buffer for the global (L2-hit) zT
    // B-fragments: loads for ks+1 issue before the 16 MFMAs of ks.
    f32x4 acc[4][4];
#pragma unroll
    for (int m = 0; m < 4; ++m)
#pragma unroll
        for (int j = 0; j < 4; ++j)
            acc[m][j] = (f32x4){0.f, 0.f, 0.f, 0.f};

    const unsigned short* zbase = zT + (size_t)(w * 64 + l15) * DDIM + quad * 8;
    bf16x8 bbuf[2][4];
#pragma unroll
    for (int j = 0; j < 4; ++j)
        bbuf[0][j] = *(const bf16x8*)(zbase + (size_t)j * 16 * DDIM);
#pragma unroll
    for (int ks = 0; ks < 16; ++ks) {
        const int cur = ks & 1;
        if (ks < 15) {
#pragma unroll
            for (int j = 0; j < 4; ++j)
                bbuf[cur ^ 1][j] = *(const bf16x8*)(zbase + (size_t)j * 16 * DDIM + (ks + 1) * 32);
        }
        bf16x8 af[4];
#pragma unroll
        for (int m = 0; m < 4; ++m) {
            int row = m * 16 + l15;
            af[m] = *(const bf16x8*)(smem + row * 1024 + (((ks * 4 + quad) ^ (row & 7)) * 16));
        }
#pragma unroll
        for (int m = 0; m < 4; ++m)
#pragma unroll
            for (int j = 0; j < 4; ++j)
                acc[m][j] = __builtin_amdgcn_mfma_f32_16x16x32_bf16(af[m], bbuf[cur][j], acc[m][j], 0, 0, 0);
    }

    // ---------------- Epilogue: in-register C-layout ----------------
    // C layout: row = m*16 + quad*4 + r, col = w*64 + j*16 + l15
    float znv[4], chc[4], shc[4];
#pragma unroll
    for (int j = 0; j < 4; ++j) {
        int col = w * 64 + j * 16 + l15;
        znv[j] = znf[col]; chc[j] = chv[col]; shc[j] = shv[col];
    }
    const float* xb = Xc + (size_t)r0 * DDIM + w * 64 + l15;

#pragma unroll
    for (int m = 0; m < 4; ++m) {
        int rbase = m * 16 + quad * 4;
        // hoist the 16 x_current re-reads (L2-hit) ahead of the transcendental math
        float xv[4][4];
#pragma unroll
        for (int j = 0; j < 4; ++j)
#pragma unroll
            for (int r = 0; r < 4; ++r)
                xv[j][r] = xb[(size_t)(rbase + r) * DDIM + j * 16];
        float inv1m[4], opc[4];
#pragma unroll
        for (int r = 0; r < 4; ++r) {
            float c2 = cx2s[rbase + r];
            inv1m[r] = rcpf(fmaxf(1.0f - c2, EPSF));
            opc[r] = 1.0f + c2;
        }
        float swr[4] = {0.f, 0.f, 0.f, 0.f}, cwr[4] = {0.f, 0.f, 0.f, 0.f};
#pragma unroll
        for (int j = 0; j < 4; ++j) {
#pragma unroll
            for (int r = 0; r < 4; ++r) {
                float inner = acc[m][j][r];
                float arg = fmaf(2.0f * inner, chc[j], -opc[r] * shc[j]) * inv1m[r];
                float v = 2.0f * znv[j] * fast_asinh(arg);
                float wv = fast_sinh(v);
                acc[m][j][r] = wv;   // overwrite accumulator with w
                swr[r] = fmaf(wv, wv, swr[r]);
                cwr[r] = fmaf(xv[j][r], wv, cwr[r]);
            }
        }
#pragma unroll
        for (int r = 0; r < 4; ++r) {
            float s = swr[r], c = cwr[r];
            s += __shfl_xor(s, 1); s += __shfl_xor(s, 2); s += __shfl_xor(s, 4); s += __shfl_xor(s, 8);
            c += __shfl_xor(c, 1); c += __shfl_xor(c, 2); c += __shfl_xor(c, 4); c += __shfl_xor(c, 8);
            if (l15 == 0) { swp[(rbase + r) * 8 + w] = s; cwp[(rbase + r) * 8 + w] = c; }
        }
    }
    __syncthreads();

    // per-row scalar chain on 64 threads
    if (t < 64) {
        int row = t;
        float4 s0 = *(const float4*)(swp + row * 8);
        float4 s1 = *(const float4*)(swp + row * 8 + 4);
        float sw = ((s0.x + s0.y) + (s0.z + s0.w)) + ((s1.x + s1.y) + (s1.z + s1.w));
        float4 q0 = *(const float4*)(cwp + row * 8);
        float4 q1 = *(const float4*)(cwp + row * 8 + 4);
        float cw = ((q0.x + q0.y) + (q0.z + q0.w)) + ((q1.x + q1.y) + (q1.z + q1.w));
        float dcc = dccs[row];
        float is = 1.0f / (1.0f + sqrtf(1.0f + sw));       // fc = is*w
        float nfc = sqrtf(fmaxf(sw * is * is, EPSF));
        float artf = fast_atanh_pos(fminf(nfc, ATANH_CLIP));
        float un2 = fmaxf(step_sig * artf, SQRT_EPSF);
        float g = fast_tanh_pos(un2 / fmaxf(1.0f - dcc, EPSF));
        float by = g * is / nfc;                           // y = by*w
        float xy = by * cw;
        float y2 = by * by * sw;
        float P = 1.0f + 2.0f * xy + y2;
        float den2 = fmaxf(1.0f + 2.0f * xy + dcc * y2, EPSF);
        float a1 = P / den2;
        float b1 = (1.0f - dcc) * by / den2;               // xur = a1*x + b1*w
        float s2u = a1 * a1 * dcc + 2.0f * a1 * b1 * cw + b1 * b1 * sw;
        float nxu = sqrtf(fmaxf(s2u, EPSF));
        float pj = (nxu > MAXNF) ? (MAXNF / nxu) : 1.0f;
        a1 *= pj; b1 *= pj;
        float nxu2 = fminf(nxu, MAXNF);
        float nx = sqrtf(fmaxf(dcc, EPSF));
        float sxc = (nx > MAXNF) ? (MAXNF / nx) : 1.0f;
        float nxc = fminf(nx, MAXNF);
        float A1 = fast_tanh_pos(a_sig * fast_atanh_pos(fminf(nxc, ATANH_CLIP))) / nxc * sxc;
        float t2s = fast_tanh_pos((1.0f - a_sig) * fast_atanh_pos(fminf(nxu2, ATANH_CLIP)));
        float sm2 = t2s / fmaxf(nxu2, SQRT_EPSF);
        float A2 = sm2 * a1, B2 = sm2 * b1;                // m2 = A2*x + B2*w
        float x2m = A1 * A1 * dcc;
        float y2m = A2 * A2 * dcc + 2.0f * A2 * B2 * cw + B2 * B2 * sw;
        float xym = A1 * (A2 * dcc + B2 * cw);
        float num1 = 1.0f + 2.0f * xym + y2m;
        float num2 = 1.0f - x2m;
        float den3 = fmaxf(1.0f + 2.0f * xym + x2m * y2m, EPSF);
        float an = (num1 * A1 + num2 * A2) / den3;
        float bn = (num2 * B2) / den3;
        float s2n = an * an * dcc + 2.0f * an * bn * cw + bn * bn * sw;
        float nn = sqrtf(fmaxf(s2n, EPSF));
        float pj2 = (nn > MAXNF) ? (MAXNF / nn) : 1.0f;
        ans[row] = an * pj2;
        bns[row] = bn * pj2;
    }
    __syncthreads();

    // store out0 from C-layout (4 rows x 64B per instr, coalesced)
    float* ob = out + (size_t)r0 * DDIM + w * 64 + l15;
#pragma unroll
    for (int m = 0; m < 4; ++m) {
        int rbase = m * 16 + quad * 4;
        float xv[4][4];
#pragma unroll
        for (int j = 0; j < 4; ++j)
#pragma unroll
            for (int r = 0; r < 4; ++r)
                xv[j][r] = xb[(size_t)(rbase + r) * DDIM + j * 16];
        float anv[4], bnv[4];
#pragma unroll
        for (int r = 0; r < 4; ++r) { anv[r] = ans[rbase + r]; bnv[r] = bns[rbase + r]; }
#pragma unroll
        for (int j = 0; j < 4; ++j) {
#pragma unroll
            for (int r = 0; r < 4; ++r)
                ob[(size_t)(rbase + r) * DDIM + j * 16] = fmaf(anv[r], xv[j][r], bnv[r] * acc[m][j][r]);
        }
    }
}

extern "C" void kernel_launch(void* const* d_in, const int* in_sizes, int n_in,
                              void* d_out, int out_size, void* d_ws, size_t ws_size,
                              hipStream_t stream) {
    const float* xc = (const float*)d_in[0];
    const float* xp = (const float*)d_in[1];
    const float* z = (const float*)d_in[2];
    const float* bias = (const float*)d_in[3];
    const float* alpha = (const float*)d_in[4];
    const float* stepsz = (const float*)d_in[5];
    float* out = (float*)d_out;

    float* znf = (float*)d_ws;            // 512 f32
    float* chv = znf + 512;               // 512 f32
    float* shv = znf + 1024;              // 512 f32
    unsigned short* zT = (unsigned short*)(znf + 1536);  // 512x512 bf16 (transposed z_unit)

    prep_kernel<<<512, 64, 0, stream>>>(z, bias, znf, chv, shv, zT);
    hpd_main<<<BROWS / 64, 512, 0, stream>>>(xc, xp, znf, chv, shv, zT, alpha, stepsz, out);
}